// Round 1
// baseline (782.070 us; speedup 1.0000x reference)
//
#include <hip/hip_runtime.h>
#include <math.h>

#define BB 4
#define HH 64
#define WW 64
#define CC 21
#define NN 4096
#define NITER 5

// exp(-0.5*d2/theta^2) = exp2(coef * d2_raw) with coef = -0.5*log2(e)/theta^2
#define CS_COEF  (-0.08014972449383172f)      // spatial: -0.5*log2e/9
#define CBC_COEF (-2.8177637517362567e-05f)   // bilateral coords: -0.5*log2e/160^2
#define SB_SCALE (0.28310726680985215f)       // rgb prescale: sqrt(0.5*log2e)/3

// record layout per (b,n): 32 floats
// [0]=y [1]=x [2..4]=rgb*SB [5..7]=pad [8..28]=p[0..20] [29..31]=pad

__global__ __launch_bounds__(64) void crf_filter(const float* __restrict__ rec,
                                                 float* __restrict__ part,
                                                 int mlen, int nmc) {
  const int mc   = blockIdx.x;
  const int nblk = blockIdx.y;   // = pixel row y (W==64, lane = x)
  const int b    = blockIdx.z;
  const int lane = threadIdx.x;

  const float yn = (float)nblk;
  const float xn = (float)lane;
  const float* recb = rec + ((size_t)b << 17);            // b*4096*32
  const float* rn = recb + ((size_t)(nblk * 64 + lane) << 5);
  const float rr = rn[2], gg = rn[3], bb2 = rn[4];

  float sp[CC], bl[CC];
#pragma unroll
  for (int c = 0; c < CC; ++c) { sp[c] = 0.f; bl[c] = 0.f; }
  float sn = 0.f, bn = 0.f;

  const int m0 = mc * mlen;
#pragma unroll 2
  for (int m = m0; m < m0 + mlen; ++m) {
    const float* rm = recb + ((size_t)m << 5);   // wave-uniform -> scalar loads
    const float ym = rm[0], xm = rm[1];
    const float dy = yn - ym, dx = xn - xm;
    const float t = fmaf(dy, dy, dx * dx);
    const float ks = __builtin_amdgcn_exp2f(CS_COEF * t);
    const float dr = rr - rm[2], dg = gg - rm[3], db = bb2 - rm[4];
    const float trgb = fmaf(db, db, fmaf(dg, dg, dr * dr));
    const float kb = __builtin_amdgcn_exp2f(fmaf(CBC_COEF, t, -trgb));
    sn += ks;
    bn += kb;
#pragma unroll
    for (int c = 0; c < CC; ++c) {
      const float pc = rm[8 + c];
      sp[c] = fmaf(ks, pc, sp[c]);
      bl[c] = fmaf(kb, pc, bl[c]);
    }
  }

  // partials: [B][64][nmc][44][64]
  float* o = part + ((((size_t)((b * 64 + nblk) * nmc + mc)) * 44) << 6) + lane;
#pragma unroll
  for (int c = 0; c < CC; ++c) {
    o[c * 64] = sp[c];
    o[(CC + c) * 64] = bl[c];
  }
  o[42 * 64] = sn;
  o[43 * 64] = bn;
}

__global__ __launch_bounds__(256) void crf_update(const float* __restrict__ unary,
                                                  const float* __restrict__ rgb,
                                                  const float* __restrict__ Ws,
                                                  const float* __restrict__ Wb,
                                                  const float* __restrict__ Cm,
                                                  const float* __restrict__ part,
                                                  float* __restrict__ rec,
                                                  float* __restrict__ dout,
                                                  int first, int last, int nmc) {
  const int tid = blockIdx.x * 256 + threadIdx.x;  // 0..16383 = b*4096+n
  const int n = tid & 4095;
  const float* up = unary + (size_t)tid * CC;

  float q[CC];
  if (!first) {
    float sp[CC], bl[CC];
#pragma unroll
    for (int c = 0; c < CC; ++c) { sp[c] = 0.f; bl[c] = 0.f; }
    float sn = 0.f, bn = 0.f;
    const int b = tid >> 12;
    const int nblk = n >> 6, lane = n & 63;
    const float* pb = part + (((size_t)(b * 64 + nblk) * nmc * 44) << 6) + lane;
    for (int mc = 0; mc < nmc; ++mc) {
      const float* pm = pb + (((size_t)mc * 44) << 6);
#pragma unroll
      for (int c = 0; c < CC; ++c) {
        sp[c] += pm[c * 64];
        bl[c] += pm[(CC + c) * 64];
      }
      sn += pm[42 * 64];
      bn += pm[43 * 64];
    }
    const float isn = 1.f / sn, ibn = 1.f / bn;
#pragma unroll
    for (int c = 0; c < CC; ++c) { sp[c] *= isn; bl[c] *= ibn; }
    float msg[CC];
    for (int c = 0; c < CC; ++c) {
      float a = 0.f;
      for (int k = 0; k < CC; ++k)
        a += Ws[c * CC + k] * sp[k] + Wb[c * CC + k] * bl[k];
      msg[c] = a;
    }
    for (int c = 0; c < CC; ++c) {
      float a = 0.f;
      for (int k = 0; k < CC; ++k) a += Cm[c * CC + k] * msg[k];
      q[c] = up[c] - a;
    }
  } else {
#pragma unroll
    for (int c = 0; c < CC; ++c) q[c] = up[c];
  }

  if (last) {
    float* op = dout + (size_t)tid * CC;
#pragma unroll
    for (int c = 0; c < CC; ++c) op[c] = q[c];
  }

  // softmax over classes + pack next record
  float mx = q[0];
#pragma unroll
  for (int c = 1; c < CC; ++c) mx = fmaxf(mx, q[c]);
  float e[CC], s = 0.f;
#pragma unroll
  for (int c = 0; c < CC; ++c) { e[c] = __expf(q[c] - mx); s += e[c]; }
  const float is = 1.f / s;

  float* r = rec + ((size_t)tid << 5);
  r[0] = (float)(n >> 6);
  r[1] = (float)(n & 63);
  const float* rg = rgb + (size_t)tid * 3;
  r[2] = rg[0] * SB_SCALE;
  r[3] = rg[1] * SB_SCALE;
  r[4] = rg[2] * SB_SCALE;
  r[5] = 0.f; r[6] = 0.f; r[7] = 0.f;
#pragma unroll
  for (int c = 0; c < CC; ++c) r[8 + c] = e[c] * is;
  r[29] = 0.f; r[30] = 0.f; r[31] = 0.f;
}

extern "C" void kernel_launch(void* const* d_in, const int* in_sizes, int n_in,
                              void* d_out, int out_size, void* d_ws, size_t ws_size,
                              hipStream_t stream) {
  const float* unary = (const float*)d_in[0];
  const float* rgb   = (const float*)d_in[1];
  const float* Ws    = (const float*)d_in[2];
  const float* Wb    = (const float*)d_in[3];
  const float* Cm    = (const float*)d_in[4];
  float* out = (float*)d_out;

  float* rec = (float*)d_ws;                         // [B][N][32] f32 = 2 MB
  const size_t rec_bytes = (size_t)BB * NN * 32 * 4;

  int nmc = 8;                                       // m-chunks (occupancy)
  if (ws_size < rec_bytes + (size_t)BB * 64 * nmc * 44 * 64 * 4) nmc = 1;
  const int mlen = NN / nmc;
  float* part = (float*)((char*)d_ws + rec_bytes);   // [B][64][nmc][44][64] f32

  // p_1 = softmax(u); pack records
  crf_update<<<dim3(64), dim3(256), 0, stream>>>(unary, rgb, Ws, Wb, Cm,
                                                 part, rec, out, 1, 0, nmc);
  for (int it = 0; it < NITER; ++it) {
    crf_filter<<<dim3(nmc, 64, BB), dim3(64), 0, stream>>>(rec, part, mlen, nmc);
    crf_update<<<dim3(64), dim3(256), 0, stream>>>(unary, rgb, Ws, Wb, Cm,
                                                   part, rec, out, 0,
                                                   (it == NITER - 1) ? 1 : 0, nmc);
  }
}

// Round 3
// 482.860 us; speedup vs baseline: 1.6197x; 1.6197x over previous
//
#include <hip/hip_runtime.h>
#include <stdint.h>
#include <math.h>

#define BB 4
#define CC 21
#define NN 4096
#define NITER 5
#define REC 48   // floats per record
#define PH 64    // m per staged phase
#define PCH 22   // channels stored in partials (21 + norm)

// exp(-0.5*d2/theta^2) = exp2(coef*d2) ; rgb prescaled so kb = exp2(CBC*t - trgb)
#define CS_COEF  (-0.08014972449383172f)      // -0.5*log2e/9
#define CBC_COEF (-2.8177637517362567e-05f)   // -0.5*log2e/160^2
#define SB_SCALE (0.28310726680985215f)       // sqrt(0.5*log2e)/3

// record: [0..2]=rgb*SB [3..7]=0 [8..28]=p[0..20] [29]=1.0 (norm ch) [30..47]=0

typedef short bf16x8 __attribute__((ext_vector_type(8)));
typedef float f32x16 __attribute__((ext_vector_type(16)));
typedef uint32_t u32;
typedef uint32_t u32x4 __attribute__((ext_vector_type(4)));

static __device__ __forceinline__ u32 pkh(float a, float b) {
  // pack truncated-bf16(a) (lo half) and truncated-bf16(b) (hi half)
  return (__builtin_bit_cast(u32, b) & 0xFFFF0000u) | (__builtin_bit_cast(u32, a) >> 16);
}
static __device__ __forceinline__ float hif(float a) {
  return __builtin_bit_cast(float, __builtin_bit_cast(u32, a) & 0xFFFF0000u);
}
static __device__ __forceinline__ bf16x8 mk(u32 a, u32 b, u32 c, u32 d) {
  u32x4 t = {a, b, c, d};
  return __builtin_bit_cast(bf16x8, t);
}

// grid (nmc, 32, B), block 256 = 4 waves. wave -> 32-n tile; chunk -> m range.
// D = K_tile(32n x 16m) . P_tile(16m x 32ch): A row = lane&31 = n-local,
// B col = lane&31 = channel; k = (lane>>5)*8 + elem for both (any shared
// k-permutation cancels in the contraction).
__global__ __launch_bounds__(256) void crf_filter(const float* __restrict__ rec,
                                                  float* __restrict__ part,
                                                  int mlen, int nmc) {
  __shared__ float lds[2][PH * REC];   // 2 x 12 KB
  const int chunk = blockIdx.x, ng = blockIdx.y, b = blockIdx.z;
  const int wave = threadIdx.x >> 6, lane = threadIdx.x & 63;
  const int c = lane & 31, h = lane >> 5;     // c = row/col, h = m-octet
  const int ntile = ng * 4 + wave;            // 0..127
  const int n = (ntile << 5) + c;
  const float yn = (float)(n >> 6);
  const float xn = (float)(n & 63);

  const float* recb = rec + (size_t)b * NN * REC;
  const float* rn = recb + (size_t)n * REC;
  const float rr = rn[0], gg = rn[1], bb2 = rn[2];

  f32x16 accs, accb;
#pragma unroll
  for (int r = 0; r < 16; ++r) { accs[r] = 0.f; accb[r] = 0.f; }

  const int m_lo = chunk * mlen;
  const int phases = mlen / PH;
  const int slot = wave * 192 + lane;         // float4 units within a 768-float4 phase

  const float4* gsrc = (const float4*)(recb + (size_t)m_lo * REC);
  float4 st0 = gsrc[slot], st1 = gsrc[slot + 64], st2 = gsrc[slot + 128];

  for (int p = 0; p < phases; ++p) {
    float* buf = lds[p & 1];
    float4* lb = (float4*)buf;
    lb[slot] = st0; lb[slot + 64] = st1; lb[slot + 128] = st2;
    __syncthreads();
    if (p + 1 < phases) {
      gsrc = (const float4*)(recb + (size_t)(m_lo + (p + 1) * PH) * REC);
      st0 = gsrc[slot]; st1 = gsrc[slot + 64]; st2 = gsrc[slot + 128];
    }
    const int mph = m_lo + p * PH;
#pragma unroll 1
    for (int s = 0; s < 4; ++s) {           // 16-m MFMA steps
      const int m0 = mph + s * 16;
      // m0 multiple of 16 -> no x-wrap inside step; y_m uniform
      const float dy = yn - (float)(m0 >> 6);
      const float dy2 = dy * dy;
      const float dx0 = xn - (float)((m0 & 63) + (h << 3));
      const float* rmb = buf + (s * 16 + (h << 3)) * REC;
      const float* pmb = rmb + 8 + c;
      u32 ash[4], asl[4], abh[4], abl[4], bh[4], bl[4];
#pragma unroll
      for (int j2 = 0; j2 < 4; ++j2) {
        const float* rm0 = rmb + (2 * j2) * REC;
        const float* rm1 = rm0 + REC;
        const float dxa = dx0 - (float)(2 * j2);
        const float dxb = dxa - 1.0f;
        const float ta = fmaf(dxa, dxa, dy2);
        const float tb = fmaf(dxb, dxb, dy2);
        const float dr0 = rr - rm0[0], dg0 = gg - rm0[1], db0 = bb2 - rm0[2];
        const float dr1 = rr - rm1[0], dg1 = gg - rm1[1], db1 = bb2 - rm1[2];
        const float ks0 = __builtin_amdgcn_exp2f(CS_COEF * ta);
        const float ks1 = __builtin_amdgcn_exp2f(CS_COEF * tb);
        const float kb0 = __builtin_amdgcn_exp2f(
            fmaf(CBC_COEF, ta, -fmaf(db0, db0, fmaf(dg0, dg0, dr0 * dr0))));
        const float kb1 = __builtin_amdgcn_exp2f(
            fmaf(CBC_COEF, tb, -fmaf(db1, db1, fmaf(dg1, dg1, dr1 * dr1))));
        ash[j2] = pkh(ks0, ks1);
        asl[j2] = pkh(ks0 - hif(ks0), ks1 - hif(ks1));
        abh[j2] = pkh(kb0, kb1);
        abl[j2] = pkh(kb0 - hif(kb0), kb1 - hif(kb1));
        const float p0 = pmb[(2 * j2) * REC];
        const float p1 = pmb[(2 * j2 + 1) * REC];
        bh[j2] = pkh(p0, p1);
        bl[j2] = pkh(p0 - hif(p0), p1 - hif(p1));
      }
      const bf16x8 Ash = mk(ash[0], ash[1], ash[2], ash[3]);
      const bf16x8 Asl = mk(asl[0], asl[1], asl[2], asl[3]);
      const bf16x8 Abh = mk(abh[0], abh[1], abh[2], abh[3]);
      const bf16x8 Abl = mk(abl[0], abl[1], abl[2], abl[3]);
      const bf16x8 Bh = mk(bh[0], bh[1], bh[2], bh[3]);
      const bf16x8 Bl = mk(bl[0], bl[1], bl[2], bl[3]);
      accs = __builtin_amdgcn_mfma_f32_32x32x16_bf16(Ash, Bh, accs, 0, 0, 0);
      accs = __builtin_amdgcn_mfma_f32_32x32x16_bf16(Ash, Bl, accs, 0, 0, 0);
      accs = __builtin_amdgcn_mfma_f32_32x32x16_bf16(Asl, Bh, accs, 0, 0, 0);
      accb = __builtin_amdgcn_mfma_f32_32x32x16_bf16(Abh, Bh, accb, 0, 0, 0);
      accb = __builtin_amdgcn_mfma_f32_32x32x16_bf16(Abh, Bl, accb, 0, 0, 0);
      accb = __builtin_amdgcn_mfma_f32_32x32x16_bf16(Abl, Bh, accb, 0, 0, 0);
    }
    __syncthreads();
  }

  // partials: [b][ntile][chunk][mat(2)][nloc(32)][ch(PCH)]
  if (c < PCH) {
    float* os = part + ((((size_t)b * 128 + ntile) * nmc + chunk) * 2) * (32 * PCH) + c;
    float* ob = os + 32 * PCH;
#pragma unroll
    for (int r = 0; r < 16; ++r) {
      const int nloc = (r & 3) + ((r >> 2) << 3) + (h << 2);
      os[nloc * PCH] = accs[r];
      ob[nloc * PCH] = accb[r];
    }
  }
}

__global__ __launch_bounds__(256) void crf_update(const float* __restrict__ unary,
                                                  const float* __restrict__ rgb,
                                                  const float* __restrict__ Ws,
                                                  const float* __restrict__ Wb,
                                                  const float* __restrict__ Cm,
                                                  const float* __restrict__ part,
                                                  float* __restrict__ rec,
                                                  float* __restrict__ dout,
                                                  int first, int last, int nmc) {
  const int tid = blockIdx.x * 256 + threadIdx.x;  // b*4096+n
  const int b = tid >> 12, n = tid & 4095;
  const float* up = unary + (size_t)tid * CC;

  float q[CC];
  if (!first) {
    float sp[PCH], bl[PCH];
#pragma unroll
    for (int c = 0; c < PCH; ++c) { sp[c] = 0.f; bl[c] = 0.f; }
    const float* pb = part + (((size_t)b * 128 + (n >> 5)) * nmc * 2) * (32 * PCH)
                      + (n & 31) * PCH;
    for (int ch = 0; ch < nmc; ++ch) {
      const float* p0 = pb + (size_t)ch * 2 * (32 * PCH);
      const float* p1 = p0 + 32 * PCH;
#pragma unroll
      for (int c = 0; c < PCH; ++c) { sp[c] += p0[c]; bl[c] += p1[c]; }
    }
    const float isn = 1.f / sp[21], ibn = 1.f / bl[21];
#pragma unroll
    for (int c = 0; c < CC; ++c) { sp[c] *= isn; bl[c] *= ibn; }
    float msg[CC];
    for (int c = 0; c < CC; ++c) {
      float a = 0.f;
      for (int k = 0; k < CC; ++k)
        a += Ws[c * CC + k] * sp[k] + Wb[c * CC + k] * bl[k];
      msg[c] = a;
    }
    for (int c = 0; c < CC; ++c) {
      float a = 0.f;
      for (int k = 0; k < CC; ++k) a += Cm[c * CC + k] * msg[k];
      q[c] = up[c] - a;
    }
  } else {
#pragma unroll
    for (int c = 0; c < CC; ++c) q[c] = up[c];
  }

  if (last) {
    float* op = dout + (size_t)tid * CC;
#pragma unroll
    for (int c = 0; c < CC; ++c) op[c] = q[c];
  }

  float mx = q[0];
#pragma unroll
  for (int c = 1; c < CC; ++c) mx = fmaxf(mx, q[c]);
  float e[CC], s = 0.f;
#pragma unroll
  for (int c = 0; c < CC; ++c) { e[c] = __expf(q[c] - mx); s += e[c]; }
  const float is = 1.f / s;

  float4* r4 = (float4*)(rec + (size_t)tid * REC);
  const float* rg = rgb + (size_t)tid * 3;
  r4[0] = make_float4(rg[0] * SB_SCALE, rg[1] * SB_SCALE, rg[2] * SB_SCALE, 0.f);
  r4[1] = make_float4(0.f, 0.f, 0.f, 0.f);
  float pv[CC];
#pragma unroll
  for (int c = 0; c < CC; ++c) pv[c] = e[c] * is;
  r4[2] = make_float4(pv[0], pv[1], pv[2], pv[3]);
  r4[3] = make_float4(pv[4], pv[5], pv[6], pv[7]);
  r4[4] = make_float4(pv[8], pv[9], pv[10], pv[11]);
  r4[5] = make_float4(pv[12], pv[13], pv[14], pv[15]);
  r4[6] = make_float4(pv[16], pv[17], pv[18], pv[19]);
  r4[7] = make_float4(pv[20], 1.0f, 0.f, 0.f);   // ones channel for norms
  r4[8] = make_float4(0.f, 0.f, 0.f, 0.f);
  r4[9] = make_float4(0.f, 0.f, 0.f, 0.f);
  r4[10] = make_float4(0.f, 0.f, 0.f, 0.f);
  r4[11] = make_float4(0.f, 0.f, 0.f, 0.f);
}

extern "C" void kernel_launch(void* const* d_in, const int* in_sizes, int n_in,
                              void* d_out, int out_size, void* d_ws, size_t ws_size,
                              hipStream_t stream) {
  const float* unary = (const float*)d_in[0];
  const float* rgb   = (const float*)d_in[1];
  const float* Ws    = (const float*)d_in[2];
  const float* Wb    = (const float*)d_in[3];
  const float* Cm    = (const float*)d_in[4];
  float* out = (float*)d_out;

  float* rec = (float*)d_ws;                           // [B][N][48] = 3 MiB
  const size_t rec_bytes = (size_t)BB * NN * REC * 4;

  int nmc = 8;                                         // m-chunks
  while (nmc > 1 &&
         ws_size < rec_bytes + (size_t)BB * 128 * nmc * 2 * 32 * PCH * 4)
    nmc >>= 1;
  const int mlen = NN / nmc;
  float* part = (float*)((char*)d_ws + rec_bytes);     // [B][128][nmc][2][32][22]

  crf_update<<<dim3(64), dim3(256), 0, stream>>>(unary, rgb, Ws, Wb, Cm,
                                                 part, rec, out, 1, 0, nmc);
  for (int it = 0; it < NITER; ++it) {
    crf_filter<<<dim3(nmc, 32, BB), dim3(256), 0, stream>>>(rec, part, mlen, nmc);
    crf_update<<<dim3(64), dim3(256), 0, stream>>>(unary, rgb, Ws, Wb, Cm,
                                                   part, rec, out, 0,
                                                   (it == NITER - 1) ? 1 : 0, nmc);
  }
}